// Round 1
// baseline (631.488 us; speedup 1.0000x reference)
//
#include <hip/hip_runtime.h>
#include <math.h>

// N=20000 nodes, E=320000 edges (+N self loops), H=4 heads, HID=128, HC=512
#define NEG 0.2f
#define BN_EPS 1e-5f

// ---------------- CSR build ----------------
__global__ void init_kernel(int* __restrict__ counts, int* __restrict__ cursor,
                            float* __restrict__ stats, int N) {
    int i = blockIdx.x * 256 + threadIdx.x;
    if (i < N) { counts[i] = 1; cursor[i] = 1; }  // slot 0 of each node = self loop
    if (i < 512) stats[i] = 0.f;
}

__global__ void hist_kernel(const int* __restrict__ dst, int* __restrict__ counts, int E) {
    int i = blockIdx.x * 256 + threadIdx.x;
    if (i < E) atomicAdd(&counts[dst[i]], 1);
}

// single-block exclusive scan of counts[0..n-1] -> offsets[0..n]
__global__ void scan_kernel(const int* __restrict__ counts, int* __restrict__ offsets, int n) {
    __shared__ int lds[1024];
    __shared__ int carry_s;
    int tid = threadIdx.x;
    if (tid == 0) carry_s = 0;
    __syncthreads();
    for (int base = 0; base < n; base += 1024) {
        int i = base + tid;
        int v = (i < n) ? counts[i] : 0;
        lds[tid] = v;
        __syncthreads();
        for (int off = 1; off < 1024; off <<= 1) {
            int t = (tid >= off) ? lds[tid - off] : 0;
            __syncthreads();
            lds[tid] += t;
            __syncthreads();
        }
        int incl = lds[tid];
        int carry = carry_s;
        if (i < n) offsets[i] = carry + incl - v;   // exclusive
        __syncthreads();
        if (tid == 1023) carry_s = carry + incl;    // tile total
        __syncthreads();
    }
    if (tid == 0) offsets[n] = carry_s;
}

__global__ void scatter_kernel(const int* __restrict__ src, const int* __restrict__ dst,
                               const int* __restrict__ offsets, int* __restrict__ cursor,
                               int* __restrict__ csr_src, int E, int N) {
    int i = blockIdx.x * 256 + threadIdx.x;
    if (i < E) {
        int d = dst[i];
        int pos = offsets[d] + atomicAdd(&cursor[d], 1);
        csr_src[pos] = src[i];
    } else if (i < E + N) {
        int n = i - E;
        csr_src[offsets[n]] = n;   // self loop at slot 0
    }
}

// ---------------- SGEMM (f32, C = A*B + bias) ----------------
// BM=128, BN=64, BK=16, 256 threads, microtile 8x4
__global__ __launch_bounds__(256) void sgemm_bias(
    const float* __restrict__ A, const float* __restrict__ B,
    const float* __restrict__ bias, float* __restrict__ C,
    int M, int Ncols, int K) {
    __shared__ float As[16][128 + 4];  // [k][m]
    __shared__ float Bs[16][64 + 4];   // [k][n]
    int tid = threadIdx.x;
    int bm = blockIdx.x * 128;
    int bn = blockIdx.y * 64;
    int tx = tid & 15, ty = tid >> 4;
    int arow = tid >> 1, acol = (tid & 1) * 8;   // A: 128x16, 8 floats/thread
    int brow = tid >> 4, bcol = (tid & 15) * 4;  // B: 16x64, 4 floats/thread
    float acc[8][4] = {};
    for (int k0 = 0; k0 < K; k0 += 16) {
        // load A tile (guard M edge)
        float4 a0, a1;
        if (bm + arow < M) {
            const float4* ap = (const float4*)&A[(size_t)(bm + arow) * K + k0 + acol];
            a0 = ap[0]; a1 = ap[1];
        } else {
            a0 = make_float4(0, 0, 0, 0); a1 = a0;
        }
        As[acol + 0][arow] = a0.x; As[acol + 1][arow] = a0.y;
        As[acol + 2][arow] = a0.z; As[acol + 3][arow] = a0.w;
        As[acol + 4][arow] = a1.x; As[acol + 5][arow] = a1.y;
        As[acol + 6][arow] = a1.z; As[acol + 7][arow] = a1.w;
        const float4 bv = *(const float4*)&B[(size_t)(k0 + brow) * Ncols + bn + bcol];
        *(float4*)&Bs[brow][bcol] = bv;
        __syncthreads();
#pragma unroll
        for (int k = 0; k < 16; ++k) {
            float a[8], b[4];
            *(float4*)&a[0] = *(const float4*)&As[k][ty * 8];
            *(float4*)&a[4] = *(const float4*)&As[k][ty * 8 + 4];
            *(float4*)&b[0] = *(const float4*)&Bs[k][tx * 4];
#pragma unroll
            for (int i = 0; i < 8; ++i)
#pragma unroll
                for (int j = 0; j < 4; ++j)
                    acc[i][j] += a[i] * b[j];
        }
        __syncthreads();
    }
#pragma unroll
    for (int i = 0; i < 8; ++i) {
        int row = bm + ty * 8 + i;
        if (row < M) {
            float4 o;
            int col = bn + tx * 4;
            o.x = acc[i][0] + bias[col + 0];
            o.y = acc[i][1] + bias[col + 1];
            o.z = acc[i][2] + bias[col + 2];
            o.w = acc[i][3] + bias[col + 3];
            *(float4*)&C[(size_t)row * Ncols + col] = o;
        }
    }
}

// ---------------- fused edge score + online softmax + aggregate ----------------
// one wave per node; lane L holds elements [8L, 8L+8) of the 512-wide (h,c) row
__global__ __launch_bounds__(256) void gat_edge_kernel(
    const int* __restrict__ offsets, const int* __restrict__ csr_src,
    const float* __restrict__ xl, const float* __restrict__ xr,
    const float* __restrict__ att, const float* __restrict__ bvec,
    float* __restrict__ prebn, int N) {
    int lane = threadIdx.x & 63;
    int n = blockIdx.x * 4 + (threadIdx.x >> 6);
    if (n >= N) return;
    int start = offsets[n], end = offsets[n + 1];
    float xrv[8], attv[8];
    {
        const float4* p = (const float4*)&xr[(size_t)n * 512 + lane * 8];
        float4 t0 = p[0], t1 = p[1];
        xrv[0] = t0.x; xrv[1] = t0.y; xrv[2] = t0.z; xrv[3] = t0.w;
        xrv[4] = t1.x; xrv[5] = t1.y; xrv[6] = t1.z; xrv[7] = t1.w;
        const float4* q = (const float4*)&att[lane * 8];
        float4 u0 = q[0], u1 = q[1];
        attv[0] = u0.x; attv[1] = u0.y; attv[2] = u0.z; attv[3] = u0.w;
        attv[4] = u1.x; attv[5] = u1.y; attv[6] = u1.z; attv[7] = u1.w;
    }
    float m = -INFINITY, d = 0.f;
    float acc[8] = {0, 0, 0, 0, 0, 0, 0, 0};
    for (int slot = start; slot < end; ++slot) {
        int s = csr_src[slot];
        float v[8];
        const float4* p = (const float4*)&xl[(size_t)s * 512 + lane * 8];
        float4 t0 = p[0], t1 = p[1];
        v[0] = t0.x; v[1] = t0.y; v[2] = t0.z; v[3] = t0.w;
        v[4] = t1.x; v[5] = t1.y; v[6] = t1.z; v[7] = t1.w;
        float pscore = 0.f;
#pragma unroll
        for (int j = 0; j < 8; ++j) {
            float t = v[j] + xrv[j];
            t = t > 0.f ? t : NEG * t;
            pscore += t * attv[j];
        }
        // reduce within 16-lane head group
        pscore += __shfl_xor(pscore, 1);
        pscore += __shfl_xor(pscore, 2);
        pscore += __shfl_xor(pscore, 4);
        pscore += __shfl_xor(pscore, 8);
        float mn = fmaxf(m, pscore);
        float scale = __expf(m - mn);      // exp(-inf)=0 on first edge
        float w = __expf(pscore - mn);
        d = d * scale + w;
#pragma unroll
        for (int j = 0; j < 8; ++j) acc[j] = acc[j] * scale + w * v[j];
        m = mn;
    }
    float inv = 1.f / d;
    float t[8];
#pragma unroll
    for (int j = 0; j < 8; ++j) {
        float u = acc[j] * inv;
        u += __shfl_xor(u, 16);    // sum over heads (h bit0)
        u += __shfl_xor(u, 32);    // (h bit1)
        t[j] = u;
    }
    if (lane < 16) {
        float o[8];
#pragma unroll
        for (int j = 0; j < 8; ++j) {
            int c = lane * 8 + j;
            float v2 = 0.25f * t[j] + bvec[c];
            o[j] = v2 > 0.f ? v2 : NEG * v2;   // leaky_relu before BN
        }
        float* dstp = &prebn[(size_t)n * 128 + lane * 8];
        *(float4*)&dstp[0] = make_float4(o[0], o[1], o[2], o[3]);
        *(float4*)&dstp[4] = make_float4(o[4], o[5], o[6], o[7]);
    }
}

// ---------------- BN stats + apply ----------------
__global__ void bn_stats_kernel(const float* __restrict__ v, float* __restrict__ stats, int N) {
    int c = threadIdx.x;  // 128
    int r0 = blockIdx.x * 160;
    int r1 = r0 + 160; if (r1 > N) r1 = N;
    float s = 0.f, ss = 0.f;
    for (int r = r0; r < r1; ++r) {
        float x = v[(size_t)r * 128 + c];
        s += x; ss += x * x;
    }
    atomicAdd(&stats[c], s);
    atomicAdd(&stats[128 + c], ss);
}

__global__ void bn_apply_kernel(const float* __restrict__ v, const float* __restrict__ stats,
                                const float* __restrict__ g, const float* __restrict__ be,
                                const float* __restrict__ skip, float* __restrict__ out,
                                int total, int N) {
    int i = blockIdx.x * 256 + threadIdx.x;
    if (i >= total) return;
    int c = i & 127;
    float invN = 1.f / (float)N;
    float mu = stats[c] * invN;
    float var = stats[128 + c] * invN - mu * mu;
    float rs = rsqrtf(var + BN_EPS);
    float x = (v[i] - mu) * rs * g[c] + be[c];
    if (skip) x += skip[i];
    out[i] = x;
}

// ---------------- host ----------------
extern "C" void kernel_launch(void* const* d_in, const int* in_sizes, int n_in,
                              void* d_out, int out_size, void* d_ws, size_t ws_size,
                              hipStream_t stream) {
    const float* x    = (const float*)d_in[0];
    const int*   ei   = (const int*)d_in[1];
    const float* Wl0  = (const float*)d_in[2];
    const float* Wr0  = (const float*)d_in[3];
    const float* bl0  = (const float*)d_in[4];
    const float* br0  = (const float*)d_in[5];
    const float* att0 = (const float*)d_in[6];
    const float* b0   = (const float*)d_in[7];
    const float* g0   = (const float*)d_in[8];
    const float* be0  = (const float*)d_in[9];
    const float* Wl1  = (const float*)d_in[10];
    const float* Wr1  = (const float*)d_in[11];
    const float* bl1  = (const float*)d_in[12];
    const float* br1  = (const float*)d_in[13];
    const float* att1 = (const float*)d_in[14];
    const float* b1   = (const float*)d_in[15];
    const float* g1   = (const float*)d_in[16];
    const float* be1  = (const float*)d_in[17];
    const float* skW  = (const float*)d_in[18];
    const float* skb  = (const float*)d_in[19];

    const int K0 = 256, K1 = 128;
    int N = in_sizes[0] / K0;   // 20000
    int E = in_sizes[1] / 2;    // 320000
    int Etot = E + N;

    // workspace layout
    char* ws = (char*)d_ws;
    size_t off = 0;
    auto alloc = [&](size_t bytes) { size_t r = off; off += (bytes + 255) & ~(size_t)255; return r; };
    int*   counts  = (int*)(ws + alloc((size_t)(N + 1) * 4));
    int*   offsets = (int*)(ws + alloc((size_t)(N + 1) * 4));
    int*   cursor  = (int*)(ws + alloc((size_t)N * 4));
    int*   csr_src = (int*)(ws + alloc((size_t)Etot * 4));
    float* stats   = (float*)(ws + alloc(512 * 4));         // [sum0,ss0,sum1,ss1] x128
    float* xlbuf   = (float*)(ws + alloc((size_t)N * 512 * 4));
    float* xrbuf   = (float*)(ws + alloc((size_t)N * 512 * 4));
    float* hbuf    = (float*)(ws + alloc((size_t)N * 128 * 4));
    float* prebn   = (float*)(ws + alloc((size_t)N * 128 * 4));
    float* l0out   = (float*)(ws + alloc((size_t)N * 128 * 4));
    float* outf    = (float*)d_out;

    const int* src = ei;        // edge_index[0]
    const int* dst = ei + E;    // edge_index[1]

    // CSR build
    init_kernel<<<(N + 255) / 256, 256, 0, stream>>>(counts, cursor, stats, N);
    hist_kernel<<<(E + 255) / 256, 256, 0, stream>>>(dst, counts, E);
    scan_kernel<<<1, 1024, 0, stream>>>(counts, offsets, N);
    scatter_kernel<<<(Etot + 255) / 256, 256, 0, stream>>>(src, dst, offsets, cursor, csr_src, E, N);

    dim3 blk(256);
    // layer0 GEMMs
    {
        dim3 g((N + 127) / 128, 512 / 64);
        sgemm_bias<<<g, blk, 0, stream>>>(x, Wl0, bl0, xlbuf, N, 512, K0);
        sgemm_bias<<<g, blk, 0, stream>>>(x, Wr0, br0, xrbuf, N, 512, K0);
        dim3 gs((N + 127) / 128, 128 / 64);
        sgemm_bias<<<gs, blk, 0, stream>>>(x, skW, skb, hbuf, N, 128, K0);
    }
    // layer0 edge + BN + skip
    gat_edge_kernel<<<(N + 3) / 4, 256, 0, stream>>>(offsets, csr_src, xlbuf, xrbuf, att0, b0, prebn, N);
    bn_stats_kernel<<<(N + 159) / 160, 128, 0, stream>>>(prebn, stats, N);
    bn_apply_kernel<<<((size_t)N * 128 + 255) / 256, 256, 0, stream>>>(prebn, stats, g0, be0, hbuf, l0out, N * 128, N);

    // layer1 GEMMs
    {
        dim3 g((N + 127) / 128, 512 / 64);
        sgemm_bias<<<g, blk, 0, stream>>>(l0out, Wl1, bl1, xlbuf, N, 512, K1);
        sgemm_bias<<<g, blk, 0, stream>>>(l0out, Wr1, br1, xrbuf, N, 512, K1);
    }
    // layer1 edge + BN
    gat_edge_kernel<<<(N + 3) / 4, 256, 0, stream>>>(offsets, csr_src, xlbuf, xrbuf, att1, b1, outf, N);
    bn_stats_kernel<<<(N + 159) / 160, 128, 0, stream>>>(outf, stats + 256, N);
    bn_apply_kernel<<<((size_t)N * 128 + 255) / 256, 256, 0, stream>>>(outf, stats + 256, g1, be1, nullptr, outf, N * 128, N);
}

// Round 2
// 406.303 us; speedup vs baseline: 1.5542x; 1.5542x over previous
//
#include <hip/hip_runtime.h>
#include <math.h>

// N=20000 nodes, E=320000 edges (+N self loops), H=4 heads, HID=128, HC=512
#define NEG 0.2f
#define BN_EPS 1e-5f

typedef __attribute__((ext_vector_type(8))) short  bf16x8;
typedef __attribute__((ext_vector_type(4))) float  f32x4;

__device__ inline unsigned short f2b(float f) {
    unsigned int u = __float_as_uint(f);
    unsigned int r = (u + 0x7fffu + ((u >> 16) & 1u)) >> 16;
    return (unsigned short)r;
}
__device__ inline float b2f_lo(unsigned int u) { return __uint_as_float(u << 16); }
__device__ inline float b2f_hi(unsigned int u) { return __uint_as_float(u & 0xffff0000u); }

// ---------------- CSR build ----------------
__global__ void init_kernel(int* __restrict__ counts, int* __restrict__ cursor,
                            float* __restrict__ stats, int N) {
    int i = blockIdx.x * 256 + threadIdx.x;
    if (i < N) { counts[i] = 1; cursor[i] = 1; }  // slot 0 of each node = self loop
    if (i < 512) stats[i] = 0.f;
}

__global__ void hist_kernel(const int* __restrict__ dst, int* __restrict__ counts, int E) {
    int i = blockIdx.x * 256 + threadIdx.x;
    if (i < E) atomicAdd(&counts[dst[i]], 1);
}

// single-block exclusive scan of counts[0..n-1] -> offsets[0..n]
__global__ void scan_kernel(const int* __restrict__ counts, int* __restrict__ offsets, int n) {
    __shared__ int lds[1024];
    __shared__ int carry_s;
    int tid = threadIdx.x;
    if (tid == 0) carry_s = 0;
    __syncthreads();
    for (int base = 0; base < n; base += 1024) {
        int i = base + tid;
        int v = (i < n) ? counts[i] : 0;
        lds[tid] = v;
        __syncthreads();
        for (int off = 1; off < 1024; off <<= 1) {
            int t = (tid >= off) ? lds[tid - off] : 0;
            __syncthreads();
            lds[tid] += t;
            __syncthreads();
        }
        int incl = lds[tid];
        int carry = carry_s;
        if (i < n) offsets[i] = carry + incl - v;   // exclusive
        __syncthreads();
        if (tid == 1023) carry_s = carry + incl;    // tile total
        __syncthreads();
    }
    if (tid == 0) offsets[n] = carry_s;
}

__global__ void scatter_kernel(const int* __restrict__ src, const int* __restrict__ dst,
                               const int* __restrict__ offsets, int* __restrict__ cursor,
                               int* __restrict__ csr_src, int E, int N) {
    int i = blockIdx.x * 256 + threadIdx.x;
    if (i < E) {
        int d = dst[i];
        int pos = offsets[d] + atomicAdd(&cursor[d], 1);
        csr_src[pos] = src[i];
    } else if (i < E + N) {
        int n = i - E;
        csr_src[offsets[n]] = n;   // self loop at slot 0
    }
}

// ---------------- f32 -> bf16 convert (x matrix) ----------------
__global__ void conv_bf16_kernel(const float* __restrict__ in, unsigned short* __restrict__ out,
                                 int total8) {
    int i = blockIdx.x * 256 + threadIdx.x;
    if (i >= total8) return;
    const float4* p = (const float4*)&in[(size_t)i * 8];
    float4 a = p[0], b = p[1];
    unsigned short o[8];
    o[0] = f2b(a.x); o[1] = f2b(a.y); o[2] = f2b(a.z); o[3] = f2b(a.w);
    o[4] = f2b(b.x); o[5] = f2b(b.y); o[6] = f2b(b.z); o[7] = f2b(b.w);
    *(uint4*)&out[(size_t)i * 8] = *(uint4*)o;
}

// ---------------- pack f32 weight W[K][N] into bf16 MFMA B-fragment layout ----------------
// frag (nb, ks): Bp[(((nb*KS + ks)*64 + lane)*8 + j] = bf16(W[ks*32 + (lane>>4)*8 + j][nb*16 + (lane&15)])
__global__ void pack_w_kernel(const float* __restrict__ W, unsigned short* __restrict__ Bp,
                              int K, int N) {
    int t = blockIdx.x * 256 + threadIdx.x;
    int KS = K >> 5;
    int total = KS * (N >> 4) * 64;
    if (t >= total) return;
    int lane = t & 63;
    int frag = t >> 6;
    int ks = frag % KS;
    int nb = frag / KS;
    int k0 = ks * 32 + (lane >> 4) * 8;
    int col = nb * 16 + (lane & 15);
    unsigned short o[8];
#pragma unroll
    for (int j = 0; j < 8; ++j) o[j] = f2b(W[(size_t)(k0 + j) * N + col]);
    *(uint4*)&Bp[(size_t)t * 8] = *(uint4*)o;
}

// ---------------- MFMA GEMM: out_bf16[M][N] = A_bf16[M][K] @ Bp + bias ----------------
// 256 threads = 4 waves. N<=512, N multiple of 128. Wave covers 32 rows x 128 cols.
__global__ __launch_bounds__(256) void gemm_mfma(
    const unsigned short* __restrict__ A, const unsigned short* __restrict__ Bp,
    const float* __restrict__ bias, unsigned short* __restrict__ out,
    int M, int N, int K) {
    int wid = threadIdx.x >> 6, lane = threadIdx.x & 63;
    int nwc = N >> 7; if (nwc > 4) nwc = 4;   // wave columns (128 cols each)
    int wm = 4 / nwc;                          // waves stacked in M
    int wrow = wid % wm, wcol = wid / wm;
    int brow = blockIdx.x * (32 * wm) + wrow * 32;

    f32x4 acc[2][8];
#pragma unroll
    for (int i = 0; i < 2; ++i)
#pragma unroll
        for (int j = 0; j < 8; ++j) acc[i][j] = (f32x4){0.f, 0.f, 0.f, 0.f};

    int r0 = brow + (lane & 15);
    int rA0 = r0 < M ? r0 : M - 1;
    int rA1 = (r0 + 16) < M ? (r0 + 16) : M - 1;
    int kofs = (lane >> 4) * 8;
    const int KS = K >> 5;

    for (int ks = 0; ks < KS; ++ks) {
        int k0 = ks * 32 + kofs;
        bf16x8 a0 = *(const bf16x8*)&A[(size_t)rA0 * K + k0];
        bf16x8 a1 = *(const bf16x8*)&A[(size_t)rA1 * K + k0];
#pragma unroll
        for (int nb = 0; nb < 8; ++nb) {
            int fn = wcol * 8 + nb;
            bf16x8 b = *(const bf16x8*)&Bp[(((size_t)fn * KS + ks) * 64 + lane) * 8];
            acc[0][nb] = __builtin_amdgcn_mfma_f32_16x16x32_bf16(a0, b, acc[0][nb], 0, 0, 0);
            acc[1][nb] = __builtin_amdgcn_mfma_f32_16x16x32_bf16(a1, b, acc[1][nb], 0, 0, 0);
        }
    }
    // epilogue: C/D col=lane&15, row=(lane>>4)*4+reg
    int crow = (lane >> 4) * 4;
    int ccol = lane & 15;
#pragma unroll
    for (int rf = 0; rf < 2; ++rf) {
#pragma unroll
        for (int nb = 0; nb < 8; ++nb) {
            int col = wcol * 128 + nb * 16 + ccol;
            float bsv = bias[col];
#pragma unroll
            for (int reg = 0; reg < 4; ++reg) {
                int row = brow + rf * 16 + crow + reg;
                if (row < M) out[(size_t)row * N + col] = f2b(acc[rf][nb][reg] + bsv);
            }
        }
    }
}

// ---------------- fused edge score + online softmax + aggregate (bf16 features) ----------------
// one wave per node; lane L holds elements [8L, 8L+8) of the 512-wide (h,c) row
__global__ __launch_bounds__(256) void gat_edge_kernel(
    const int* __restrict__ offsets, const int* __restrict__ csr_src,
    const unsigned short* __restrict__ xl, const unsigned short* __restrict__ xr,
    const float* __restrict__ att, const float* __restrict__ bvec,
    float* __restrict__ prebn, int N) {
    int lane = threadIdx.x & 63;
    int n = blockIdx.x * 4 + (threadIdx.x >> 6);
    if (n >= N) return;
    int start = offsets[n], end = offsets[n + 1];
    float xrv[8], attv[8];
    {
        uint4 u = *(const uint4*)&xr[(size_t)n * 512 + lane * 8];
        xrv[0] = b2f_lo(u.x); xrv[1] = b2f_hi(u.x);
        xrv[2] = b2f_lo(u.y); xrv[3] = b2f_hi(u.y);
        xrv[4] = b2f_lo(u.z); xrv[5] = b2f_hi(u.z);
        xrv[6] = b2f_lo(u.w); xrv[7] = b2f_hi(u.w);
        const float4* q = (const float4*)&att[lane * 8];
        float4 u0 = q[0], u1 = q[1];
        attv[0] = u0.x; attv[1] = u0.y; attv[2] = u0.z; attv[3] = u0.w;
        attv[4] = u1.x; attv[5] = u1.y; attv[6] = u1.z; attv[7] = u1.w;
    }
    float m = -INFINITY, d = 0.f;
    float acc[8] = {0, 0, 0, 0, 0, 0, 0, 0};
    for (int slot = start; slot < end; ++slot) {
        int s = csr_src[slot];
        float v[8];
        uint4 u = *(const uint4*)&xl[(size_t)s * 512 + lane * 8];
        v[0] = b2f_lo(u.x); v[1] = b2f_hi(u.x);
        v[2] = b2f_lo(u.y); v[3] = b2f_hi(u.y);
        v[4] = b2f_lo(u.z); v[5] = b2f_hi(u.z);
        v[6] = b2f_lo(u.w); v[7] = b2f_hi(u.w);
        float pscore = 0.f;
#pragma unroll
        for (int j = 0; j < 8; ++j) {
            float t = v[j] + xrv[j];
            t = t > 0.f ? t : NEG * t;
            pscore += t * attv[j];
        }
        // reduce within 16-lane head group
        pscore += __shfl_xor(pscore, 1);
        pscore += __shfl_xor(pscore, 2);
        pscore += __shfl_xor(pscore, 4);
        pscore += __shfl_xor(pscore, 8);
        float mn = fmaxf(m, pscore);
        float scale = __expf(m - mn);      // exp(-inf)=0 on first edge
        float w = __expf(pscore - mn);
        d = d * scale + w;
#pragma unroll
        for (int j = 0; j < 8; ++j) acc[j] = acc[j] * scale + w * v[j];
        m = mn;
    }
    float inv = 1.f / d;
    float t[8];
#pragma unroll
    for (int j = 0; j < 8; ++j) {
        float u = acc[j] * inv;
        u += __shfl_xor(u, 16);    // sum over heads (h bit0)
        u += __shfl_xor(u, 32);    // (h bit1)
        t[j] = u;
    }
    if (lane < 16) {
        float o[8];
#pragma unroll
        for (int j = 0; j < 8; ++j) {
            int c = lane * 8 + j;
            float v2 = 0.25f * t[j] + bvec[c];
            o[j] = v2 > 0.f ? v2 : NEG * v2;   // leaky_relu before BN
        }
        float* dstp = &prebn[(size_t)n * 128 + lane * 8];
        *(float4*)&dstp[0] = make_float4(o[0], o[1], o[2], o[3]);
        *(float4*)&dstp[4] = make_float4(o[4], o[5], o[6], o[7]);
    }
}

// ---------------- BN stats + apply ----------------
__global__ void bn_stats_kernel(const float* __restrict__ v, float* __restrict__ stats, int N) {
    int c = threadIdx.x;  // 128
    int r0 = blockIdx.x * 160;
    int r1 = r0 + 160; if (r1 > N) r1 = N;
    float s = 0.f, ss = 0.f;
    for (int r = r0; r < r1; ++r) {
        float x = v[(size_t)r * 128 + c];
        s += x; ss += x * x;
    }
    atomicAdd(&stats[c], s);
    atomicAdd(&stats[128 + c], ss);
}

// out16 non-null -> write bf16 (layer0, with bf16 skip); outf non-null -> write f32 (layer1)
__global__ void bn_apply_kernel(const float* __restrict__ v, const float* __restrict__ stats,
                                const float* __restrict__ g, const float* __restrict__ be,
                                const unsigned short* __restrict__ skip16,
                                float* __restrict__ outf, unsigned short* __restrict__ out16,
                                int total, int N) {
    int i = blockIdx.x * 256 + threadIdx.x;
    if (i >= total) return;
    int c = i & 127;
    float invN = 1.f / (float)N;
    float mu = stats[c] * invN;
    float var = stats[128 + c] * invN - mu * mu;
    float rs = rsqrtf(var + BN_EPS);
    float x = (v[i] - mu) * rs * g[c] + be[c];
    if (skip16) x += b2f_lo((unsigned int)skip16[i]);
    if (out16) out16[i] = f2b(x);
    else outf[i] = x;
}

// ---------------- host ----------------
extern "C" void kernel_launch(void* const* d_in, const int* in_sizes, int n_in,
                              void* d_out, int out_size, void* d_ws, size_t ws_size,
                              hipStream_t stream) {
    const float* x    = (const float*)d_in[0];
    const int*   ei   = (const int*)d_in[1];
    const float* Wl0  = (const float*)d_in[2];
    const float* Wr0  = (const float*)d_in[3];
    const float* bl0  = (const float*)d_in[4];
    const float* br0  = (const float*)d_in[5];
    const float* att0 = (const float*)d_in[6];
    const float* b0   = (const float*)d_in[7];
    const float* g0   = (const float*)d_in[8];
    const float* be0  = (const float*)d_in[9];
    const float* Wl1  = (const float*)d_in[10];
    const float* Wr1  = (const float*)d_in[11];
    const float* bl1  = (const float*)d_in[12];
    const float* br1  = (const float*)d_in[13];
    const float* att1 = (const float*)d_in[14];
    const float* b1   = (const float*)d_in[15];
    const float* g1   = (const float*)d_in[16];
    const float* be1  = (const float*)d_in[17];
    const float* skW  = (const float*)d_in[18];
    const float* skb  = (const float*)d_in[19];

    const int K0 = 256, K1 = 128;
    int N = in_sizes[0] / K0;   // 20000
    int E = in_sizes[1] / 2;    // 320000
    int Etot = E + N;

    // workspace layout
    char* ws = (char*)d_ws;
    size_t off = 0;
    auto alloc = [&](size_t bytes) { size_t r = off; off += (bytes + 255) & ~(size_t)255; return r; };
    int*   counts  = (int*)(ws + alloc((size_t)(N + 1) * 4));
    int*   offsets = (int*)(ws + alloc((size_t)(N + 1) * 4));
    int*   cursor  = (int*)(ws + alloc((size_t)N * 4));
    int*   csr_src = (int*)(ws + alloc((size_t)Etot * 4));
    float* stats   = (float*)(ws + alloc(512 * 4));
    unsigned short* xb     = (unsigned short*)(ws + alloc((size_t)N * 256 * 2));
    unsigned short* xl16   = (unsigned short*)(ws + alloc((size_t)N * 512 * 2));
    unsigned short* xr16   = (unsigned short*)(ws + alloc((size_t)N * 512 * 2));
    unsigned short* hbuf16 = (unsigned short*)(ws + alloc((size_t)N * 128 * 2));
    unsigned short* l0out  = (unsigned short*)(ws + alloc((size_t)N * 128 * 2));
    float* prebn   = (float*)(ws + alloc((size_t)N * 128 * 4));
    unsigned short* Wl0p = (unsigned short*)(ws + alloc((size_t)K0 * 512 * 2));
    unsigned short* Wr0p = (unsigned short*)(ws + alloc((size_t)K0 * 512 * 2));
    unsigned short* skWp = (unsigned short*)(ws + alloc((size_t)K0 * 128 * 2));
    unsigned short* Wl1p = (unsigned short*)(ws + alloc((size_t)K1 * 512 * 2));
    unsigned short* Wr1p = (unsigned short*)(ws + alloc((size_t)K1 * 512 * 2));
    float* outf = (float*)d_out;

    const int* src = ei;        // edge_index[0]
    const int* dst = ei + E;    // edge_index[1]

    // CSR build
    init_kernel<<<(N + 255) / 256, 256, 0, stream>>>(counts, cursor, stats, N);
    hist_kernel<<<(E + 255) / 256, 256, 0, stream>>>(dst, counts, E);
    scan_kernel<<<1, 1024, 0, stream>>>(counts, offsets, N);
    scatter_kernel<<<(Etot + 255) / 256, 256, 0, stream>>>(src, dst, offsets, cursor, csr_src, E, N);

    // input + weight conversion/packing
    conv_bf16_kernel<<<((size_t)N * 256 / 8 + 255) / 256, 256, 0, stream>>>(x, xb, N * 256 / 8);
    pack_w_kernel<<<((K0 / 32) * (512 / 16) * 64 + 255) / 256, 256, 0, stream>>>(Wl0, Wl0p, K0, 512);
    pack_w_kernel<<<((K0 / 32) * (512 / 16) * 64 + 255) / 256, 256, 0, stream>>>(Wr0, Wr0p, K0, 512);
    pack_w_kernel<<<((K0 / 32) * (128 / 16) * 64 + 255) / 256, 256, 0, stream>>>(skW, skWp, K0, 128);
    pack_w_kernel<<<((K1 / 32) * (512 / 16) * 64 + 255) / 256, 256, 0, stream>>>(Wl1, Wl1p, K1, 512);
    pack_w_kernel<<<((K1 / 32) * (512 / 16) * 64 + 255) / 256, 256, 0, stream>>>(Wr1, Wr1p, K1, 512);

    // layer0 GEMMs (MFMA)
    gemm_mfma<<<(N + 31) / 32, 256, 0, stream>>>(xb, Wl0p, bl0, xl16, N, 512, K0);
    gemm_mfma<<<(N + 31) / 32, 256, 0, stream>>>(xb, Wr0p, br0, xr16, N, 512, K0);
    gemm_mfma<<<(N + 127) / 128, 256, 0, stream>>>(xb, skWp, skb, hbuf16, N, 128, K0);

    // layer0 edge + BN + skip
    gat_edge_kernel<<<(N + 3) / 4, 256, 0, stream>>>(offsets, csr_src, xl16, xr16, att0, b0, prebn, N);
    bn_stats_kernel<<<(N + 159) / 160, 128, 0, stream>>>(prebn, stats, N);
    bn_apply_kernel<<<((size_t)N * 128 + 255) / 256, 256, 0, stream>>>(
        prebn, stats, g0, be0, hbuf16, nullptr, l0out, N * 128, N);

    // layer1 GEMMs (MFMA)
    gemm_mfma<<<(N + 31) / 32, 256, 0, stream>>>(l0out, Wl1p, bl1, xl16, N, 512, K1);
    gemm_mfma<<<(N + 31) / 32, 256, 0, stream>>>(l0out, Wr1p, br1, xr16, N, 512, K1);

    // layer1 edge + BN
    gat_edge_kernel<<<(N + 3) / 4, 256, 0, stream>>>(offsets, csr_src, xl16, xr16, att1, b1, prebn, N);
    bn_stats_kernel<<<(N + 159) / 160, 128, 0, stream>>>(prebn, stats + 256, N);
    bn_apply_kernel<<<((size_t)N * 128 + 255) / 256, 256, 0, stream>>>(
        prebn, stats + 256, g1, be1, nullptr, outf, nullptr, N * 128, N);
}